// Round 11
// baseline (4706.952 us; speedup 1.0000x reference)
//
#include <hip/hip_runtime.h>
#include <math.h>

// ConvLSTM encoder, MI355X. Batch-persistent: one block per batch element,
// 256 threads (4 waves). R11: LDS cut to 74.6 KB (single h buffers with
// delayed-write staging; x-im2col gathered JIT from input) so 2 blocks/CU
// co-reside -> 2 waves/SIMD TLP. h0/h1 bf16 in LDS (single buffers),
// c0 fp32 in LDS, c1 fp32 in registers. Convs = MFMA GEMMs, B-fragment
// unroll-2 ping-pong prefetch from L2, A-fragments JIT from LDS.

typedef __bf16 bf16x8 __attribute__((ext_vector_type(8)));
typedef float  f32x4  __attribute__((ext_vector_type(4)));

__device__ __forceinline__ float sigm(float x)  { return 1.f / (1.f + __expf(-x)); }
__device__ __forceinline__ float ftanh(float x) { float e = __expf(2.f * x); return 1.f - 2.f / (e + 1.f); }

// ---------------- workspace layout (bytes) ----------------
#define OFF_WP0  ((size_t)0)          // [2][10][4][64][8] bf16 = 81,920
#define OFF_WP1  ((size_t)81920)      // [4][27][4][64][8] bf16 = 442,368
#define OFF_WFC  ((size_t)524288)     // [168][64][64] bf16 = 1,376,256
#define WS_NEED  ((size_t)1900544)

// ---------------- weight pack kernels (fragment-ordered) ----------------
// wp0f[((chh*10+s)*4+g)*512 + L*8 + e] = W0(n = g*32+chh*16+(L&15),
//   k = s*32+(L>>4)*8+e); k-order: phys s=0 -> im2col-x chunk (k<18 real),
//   phys s=1..9 -> h0 taps 0..8.
__global__ void pack_w0(const float* __restrict__ wx0, const float* __restrict__ wh0,
                        __bf16* __restrict__ dst) {
  int o = blockIdx.x * 256 + threadIdx.x;
  if (o >= 40960) return;
  int e = o & 7, L = (o >> 3) & 63;
  int idx = o >> 9;
  int g = idx & 3, sidx = idx >> 2;
  int s = sidx % 10, chh = sidx / 10;
  int n = g * 32 + chh * 16 + (L & 15);
  int k = s * 32 + (L >> 4) * 8 + e;
  float v = 0.f;
  if (k < 32) {
    if (k < 18) {
      int ky = k / 6, rem = k - ky * 6, kx = rem >> 1, ci = rem & 1;
      v = wx0[(n * 2 + ci) * 9 + ky * 3 + kx];
    }
  } else {
    int tk = k - 32, tap = tk >> 5, c = tk & 31;
    v = wh0[(n * 32 + c) * 9 + tap];
  }
  dst[o] = (__bf16)v;
}

// wp1f[((chq*27+s)*4+g)*512 + L*8 + e]: s=0..8 -> Wx1 taps (on h0(t), cin=32);
// s=9..26 -> Wh1 (tap,half) chunks (cin=64).
__global__ void pack_w1(const float* __restrict__ wx1, const float* __restrict__ wh1,
                        __bf16* __restrict__ dst) {
  int o = blockIdx.x * 256 + threadIdx.x;
  if (o >= 221184) return;
  int e = o & 7, L = (o >> 3) & 63;
  int idx = o >> 9;
  int g = idx & 3, sidx = idx >> 2;
  int s = sidx % 27, chq = sidx / 27;
  int n = g * 64 + chq * 16 + (L & 15);
  int k = s * 32 + (L >> 4) * 8 + e;
  float v;
  if (k < 288) {
    int tap = k >> 5, c = k & 31;
    v = wx1[(n * 32 + c) * 9 + tap];
  } else {
    int tk = k - 288, s2 = tk >> 5, c = tk & 31, tap = s2 >> 1, hf = s2 & 1;
    v = wh1[(n * 64 + hf * 32 + c) * 9 + tap];
  }
  dst[o] = (__bf16)v;
}

// Wfc2[pix][ch][n] bf16 = fc1_w[n][ch*168+pix]
__global__ void pack_wfc(const float* __restrict__ w, __bf16* __restrict__ dst) {
  int o = blockIdx.x * 256 + threadIdx.x;
  if (o >= 168 * 64 * 64) return;
  int pix = o >> 12, ch = (o >> 6) & 63, n = o & 63;
  dst[o] = (__bf16)w[n * 10752 + ch * 168 + pix];
}

// ---------------- the persistent ConvLSTM kernel ----------------
__global__ __launch_bounds__(256) void convlstm_persistent(
    const float* __restrict__ input, const float* __restrict__ x_ex,
    const __bf16* __restrict__ wp0, const __bf16* __restrict__ wp1,
    const __bf16* __restrict__ wfc2,
    const float* __restrict__ bx0, const float* __restrict__ bx1,
    const float* __restrict__ wc0, const float* __restrict__ wc1,
    const float* __restrict__ fc1b,
    const float* __restrict__ exw, const float* __restrict__ exb,
    float* __restrict__ out)
{
  __shared__ __bf16 sh0[9 * 26 * 40];   // h0 halo [y][x][40]   18,720 B
  __shared__ __bf16 sh1[9 * 26 * 72];   // h1 halo [y][x][72]   33,696 B
  __shared__ float  c0l[168 * 33];      // c0 fp32 [pix][33]    22,176 B
  // total 74,592 B -> 2 blocks/CU -> 2 waves/SIMD

  const int b = blockIdx.x;
  const int t = threadIdx.x;
  const int w = t >> 6, L = t & 63;
  const int lo16 = L & 15, hi4 = L >> 4;

  // ---- zero LDS ----
  {
    int* p0 = (int*)sh0;
    for (int i = t; i < 9 * 26 * 40 / 2; i += 256) p0[i] = 0;
    int* p1 = (int*)sh1;
    for (int i = t; i < 9 * 26 * 72 / 2; i += 256) p1[i] = 0;
    for (int i = t; i < 168 * 33; i += 256) c0l[i] = 0.f;
  }

  // ---- per-wave / per-lane constants ----
  const int mh = w >> 1, chh = w & 1;   // layer-0 wave role
  const int ch0 = chh * 16 + lo16;      // layer-0 channel (0..31)
  const int ch1 = w * 16 + lo16;        // layer-1 channel (0..63)

  const __bf16* w0f = wp0 + chh * 20480 + (size_t)L * 8;  // + (s*4+g)*512
  const __bf16* w1f = wp1 + w * 55296 + (size_t)L * 8;    // + (s*4+g)*512

  const float bi0 = bx0[ch0], bf0 = bx0[32 + ch0];
  const float bg0 = bx0[64 + ch0], bo0 = bx0[96 + ch0];
  const float bi1 = bx1[ch1], bf1 = bx1[64 + ch1];
  const float bg1 = bx1[128 + ch1], bo1 = bx1[192 + ch1];

  // l0 tile bases (halo addr) per pass q, tile j
  int b0h[2][3];
#pragma unroll
  for (int q = 0; q < 2; ++q)
#pragma unroll
    for (int j = 0; j < 3; ++j) {
      int pr = (mh * 6 + q * 3 + j) * 16 + lo16;
      if (pr > 167) pr = 167;
      int iy = pr / 24, ix = pr - iy * 24;
      b0h[q][j] = (iy * 26 + ix) * 40;
    }

  float c1r[3][4][4];
#pragma unroll
  for (int p = 0; p < 3; ++p)
#pragma unroll
    for (int j = 0; j < 4; ++j)
#pragma unroll
      for (int r = 0; r < 4; ++r) c1r[p][j][r] = 0.f;

  // pack two floats -> bf16x2 in a uint
  auto pk2 = [](float a, float bb) -> unsigned {
    __bf16 xa = (__bf16)a, xb = (__bf16)bb;
    unsigned short ua, ub;
    __builtin_memcpy(&ua, &xa, 2);
    __builtin_memcpy(&ub, &xb, 2);
    return (unsigned)ua | ((unsigned)ub << 16);
  };

  unsigned short* sh0u = (unsigned short*)sh0;
  unsigned short* sh1u = (unsigned short*)sh1;

  __syncthreads();   // zeroed state visible

#pragma unroll 1
  for (int st = 0; st < 7; ++st) {
    // ======================= layer 0 =======================
    unsigned st0[6];   // q0 staged h (12 bf16)
    f32x4 a0[4][3];

    // JIT x-fragment gather (time-constant values, re-gathered per pass;
    // loads issue here and are consumed at the LAST K-step of the pass)
    auto gatherX = [&](int q, bf16x8* xf) {
#pragma unroll
      for (int j = 0; j < 3; ++j) {
        int pr = (mh * 6 + q * 3 + j) * 16 + lo16;
        if (pr > 167) pr = 167;
        int py = pr / 24, pxx = pr - py * 24;
#pragma unroll
        for (int e = 0; e < 8; ++e) {
          int k = hi4 * 8 + e;
          float v = 0.f;
          if (k < 18) {
            int ky = k / 6, rem = k - ky * 6, kx = rem >> 1, ci = rem & 1;
            int y = py + ky - 1, x = pxx + kx - 1;
            if (y >= 0 && y < 7 && x >= 0 && x < 24)
              v = input[((b * 2 + ci) * 7 + y) * 24 + x];
          }
          xf[j][e] = (__bf16)v;
        }
      }
    };
    auto loadB0 = [&](int sl, bf16x8* bc) {   // logical: 0..8 taps, 9 = x
      int phys = (sl == 9) ? 0 : sl + 1;
#pragma unroll
      for (int g = 0; g < 4; ++g)
        bc[g] = *(const bf16x8*)(w0f + (phys * 4 + g) * 512);
    };
    auto mfma0 = [&](bf16x8* af, bf16x8* bc) {
#pragma unroll
      for (int j = 0; j < 3; ++j)
#pragma unroll
        for (int g = 0; g < 4; ++g)
          a0[g][j] = __builtin_amdgcn_mfma_f32_16x16x32_bf16(af[j], bc[g], a0[g][j], 0, 0, 0);
    };
    auto runK0 = [&](int q) {
#pragma unroll
      for (int g = 0; g < 4; ++g)
#pragma unroll
        for (int j = 0; j < 3; ++j) a0[g][j] = (f32x4){0.f, 0.f, 0.f, 0.f};
      bf16x8 xf[3];
      gatherX(q, xf);
      bf16x8 bcA[4], bcB[4], afT[3];
      loadB0(0, bcA); loadB0(1, bcB);
#pragma unroll 1
      for (int sl = 0; sl < 8; sl += 2) {
        {
          int ky = sl / 3, kx = sl - ky * 3;
          int toff = (ky * 26 + kx) * 40 + hi4 * 8;
#pragma unroll
          for (int j = 0; j < 3; ++j) afT[j] = *(const bf16x8*)(sh0 + b0h[q][j] + toff);
        }
        mfma0(afT, bcA);
        loadB0(sl + 2, bcA);
        {
          int sl1 = sl + 1;
          int ky = sl1 / 3, kx = sl1 - ky * 3;
          int toff = (ky * 26 + kx) * 40 + hi4 * 8;
#pragma unroll
          for (int j = 0; j < 3; ++j) afT[j] = *(const bf16x8*)(sh0 + b0h[q][j] + toff);
        }
        mfma0(afT, bcB);
        loadB0(sl + 3, bcB);
      }
      {  // tap 8 (bcA holds logical 8)
        int toff = (2 * 26 + 2) * 40 + hi4 * 8;
#pragma unroll
        for (int j = 0; j < 3; ++j) afT[j] = *(const bf16x8*)(sh0 + b0h[q][j] + toff);
        mfma0(afT, bcA);
      }
      mfma0(xf, bcB);   // x-step (bcB holds logical 9)
    };

    // ---- pass q0: K + epilogue(stage) ----
    runK0(0);
#pragma unroll
    for (int j = 0; j < 3; ++j) {
#pragma unroll
      for (int r = 0; r < 4; r += 2) {
        float hn2[2];
#pragma unroll
        for (int rr = 0; rr < 2; ++rr) {
          int r2 = r + rr;
          int p = (mh * 6 + j) * 16 + hi4 * 4 + r2;
          float c = c0l[p * 33 + ch0];
          float gi = a0[0][j][r2] + bi0;
          float gf = a0[1][j][r2] + bf0;
          float gc = a0[2][j][r2] + bg0;
          float go = a0[3][j][r2] + bo0;
          float wci = wc0[ch0 * 168 + p];
          float wcf = wc0[5376 + ch0 * 168 + p];
          float wco = wc0[10752 + ch0 * 168 + p];
          float ig = sigm(gi + c * wci);
          float fg = sigm(gf + c * wcf);
          float cn = fg * c + ig * ftanh(gc);
          float og = sigm(go + cn * wco);
          c0l[p * 33 + ch0] = cn;
          hn2[rr] = og * ftanh(cn);
        }
        st0[j * 2 + (r >> 1)] = pk2(hn2[0], hn2[1]);
      }
    }

    // ---- pass q1: K, then barrier, commit q0, direct-write q1 ----
    runK0(1);
    __syncthreads();   // all h0(t-1) reads done
#pragma unroll
    for (int j = 0; j < 3; ++j)
#pragma unroll
      for (int r = 0; r < 4; ++r) {
        int p = (mh * 6 + j) * 16 + hi4 * 4 + r;
        int iy = p / 24, ix = p - iy * 24;
        unsigned v = st0[j * 2 + (r >> 1)] >> ((r & 1) * 16);
        sh0u[((iy + 1) * 26 + ix + 1) * 40 + ch0] = (unsigned short)v;
      }
#pragma unroll
    for (int j = 0; j < 3; ++j) {
#pragma unroll
      for (int r = 0; r < 4; ++r) {
        int p = (mh * 6 + 3 + j) * 16 + hi4 * 4 + r;
        if (p < 168) {
          float c = c0l[p * 33 + ch0];
          float gi = a0[0][j][r] + bi0;
          float gf = a0[1][j][r] + bf0;
          float gc = a0[2][j][r] + bg0;
          float go = a0[3][j][r] + bo0;
          float wci = wc0[ch0 * 168 + p];
          float wcf = wc0[5376 + ch0 * 168 + p];
          float wco = wc0[10752 + ch0 * 168 + p];
          float ig = sigm(gi + c * wci);
          float fg = sigm(gf + c * wcf);
          float cn = fg * c + ig * ftanh(gc);
          float og = sigm(go + cn * wco);
          float hn = og * ftanh(cn);
          c0l[p * 33 + ch0] = cn;
          int iy = p / 24, ix = p - iy * 24;
          sh0[((iy + 1) * 26 + ix + 1) * 40 + ch0] = (__bf16)hn;
        }
      }
    }
    __syncthreads();   // h0(t) visible

    // ======================= layer 1 =======================
    f32x4 a1[4][4];
    auto loadB1 = [&](int s, bf16x8* bc) {
#pragma unroll
      for (int g = 0; g < 4; ++g)
        bc[g] = *(const bf16x8*)(w1f + (s * 4 + g) * 512);
    };
    auto runK1 = [&](int p3, int ntp) {
      int b1h0[4], b1h1[4];
#pragma unroll
      for (int j = 0; j < 4; ++j) {
        int pr = (p3 * 4 + j) * 16 + lo16;
        if (pr > 167) pr = 167;
        int iy = pr / 24, ix = pr - iy * 24;
        b1h0[j] = (iy * 26 + ix) * 40;
        b1h1[j] = (iy * 26 + ix) * 72;
      }
#pragma unroll
      for (int g = 0; g < 4; ++g)
#pragma unroll
        for (int j = 0; j < 4; ++j) a1[g][j] = (f32x4){0.f, 0.f, 0.f, 0.f};
      auto loadA1 = [&](int s, bf16x8* af) {
        if (s < 9) {
          int ky = s / 3, kx = s - ky * 3;
          int toff = (ky * 26 + kx) * 40 + hi4 * 8;
#pragma unroll
          for (int j = 0; j < 4; ++j)
            if (j < ntp) af[j] = *(const bf16x8*)(sh0 + b1h0[j] + toff);
        } else {
          int t2 = s - 9, tap = t2 >> 1, hf = t2 & 1;
          int ky = tap / 3, kx = tap - ky * 3;
          int toff = (ky * 26 + kx) * 72 + hf * 32 + hi4 * 8;
#pragma unroll
          for (int j = 0; j < 4; ++j)
            if (j < ntp) af[j] = *(const bf16x8*)(sh1 + b1h1[j] + toff);
        }
      };
      auto mfma1 = [&](bf16x8* af, bf16x8* bc) {
#pragma unroll
        for (int j = 0; j < 4; ++j)
          if (j < ntp)
#pragma unroll
            for (int g = 0; g < 4; ++g)
              a1[g][j] = __builtin_amdgcn_mfma_f32_16x16x32_bf16(af[j], bc[g], a1[g][j], 0, 0, 0);
      };
      bf16x8 bcA[4], bcB[4], afT[4];
      loadB1(0, bcA); loadB1(1, bcB);
#pragma unroll 1
      for (int s = 0; s < 26; s += 2) {
        loadA1(s, afT);  mfma1(afT, bcA);
        loadB1((s + 2 < 27) ? s + 2 : 26, bcA);
        loadA1(s + 1, afT); mfma1(afT, bcB);
        loadB1((s + 3 < 27) ? s + 3 : 26, bcB);
      }
      loadA1(26, afT); mfma1(afT, bcA);
    };
    // epilogue -> stage (passes 0,1); returns packed bf16 pairs
    auto epi1_stage = [&](int p3, unsigned* stg) {
#pragma unroll
      for (int j = 0; j < 4; ++j) {
#pragma unroll
        for (int r = 0; r < 4; r += 2) {
          float hn2[2];
#pragma unroll
          for (int rr = 0; rr < 2; ++rr) {
            int r2 = r + rr;
            int p = (p3 * 4 + j) * 16 + hi4 * 4 + r2;
            float c = c1r[p3][j][r2];
            float gi = a1[0][j][r2] + bi1;
            float gf = a1[1][j][r2] + bf1;
            float gc = a1[2][j][r2] + bg1;
            float go = a1[3][j][r2] + bo1;
            float wci = wc1[ch1 * 168 + p];
            float wcf = wc1[10752 + ch1 * 168 + p];
            float wco = wc1[21504 + ch1 * 168 + p];
            float ig = sigm(gi + c * wci);
            float fg = sigm(gf + c * wcf);
            float cn = fg * c + ig * ftanh(gc);
            float og = sigm(go + cn * wco);
            c1r[p3][j][r2] = cn;
            hn2[rr] = og * ftanh(cn);
          }
          stg[j * 2 + (r >> 1)] = pk2(hn2[0], hn2[1]);
        }
      }
    };
    auto commit1 = [&](int p3, const unsigned* stg) {
#pragma unroll
      for (int j = 0; j < 4; ++j)
#pragma unroll
        for (int r = 0; r < 4; ++r) {
          int p = (p3 * 4 + j) * 16 + hi4 * 4 + r;
          int iy = p / 24, ix = p - iy * 24;
          unsigned v = stg[j * 2 + (r >> 1)] >> ((r & 1) * 16);
          sh1u[((iy + 1) * 26 + ix + 1) * 72 + ch1] = (unsigned short)v;
        }
    };

    unsigned stg[8];
    runK1(0, 4);
    epi1_stage(0, stg);
    runK1(1, 4);
    __syncthreads();            // readers of h1(t-1) rows 0-2 done
    commit1(0, stg);
    epi1_stage(1, stg);
    runK1(2, 3);
    __syncthreads();            // all h1(t-1) reads done
    commit1(1, stg);
    // pass-2 epilogue: direct write (masked)
#pragma unroll
    for (int j = 0; j < 3; ++j) {
#pragma unroll
      for (int r = 0; r < 4; ++r) {
        int p = (8 + j) * 16 + hi4 * 4 + r;
        if (p < 168) {
          float c = c1r[2][j][r];
          float gi = a1[0][j][r] + bi1;
          float gf = a1[1][j][r] + bf1;
          float gc = a1[2][j][r] + bg1;
          float go = a1[3][j][r] + bo1;
          float wci = wc1[ch1 * 168 + p];
          float wcf = wc1[10752 + ch1 * 168 + p];
          float wco = wc1[21504 + ch1 * 168 + p];
          float ig = sigm(gi + c * wci);
          float fg = sigm(gf + c * wcf);
          float cn = fg * c + ig * ftanh(gc);
          float og = sigm(go + cn * wco);
          float hn = og * ftanh(cn);
          c1r[2][j][r] = cn;
          int iy = p / 24, ix = p - iy * 24;
          sh1[((iy + 1) * 26 + ix + 1) * 72 + ch1] = (__bf16)hn;
        }
      }
    }
    __syncthreads();   // h1(t) complete
  }

  // ================= FC heads (h1 final in sh1) =================
  {
    const int o = t & 3, pg = t >> 2;    // o: 16 n's (o*16..); pg 0..63
    float part[16];
#pragma unroll
    for (int q = 0; q < 16; ++q) part[q] = 0.f;
#pragma unroll 1
    for (int jj = 0; jj < 3; ++jj) {
      int p = pg + 64 * jj;
      if (p < 168) {
        int iy = p / 24, ix = p - iy * 24;
        const __bf16* hrow = sh1 + ((iy + 1) * 26 + ix + 1) * 72;
        const __bf16* wrow = wfc2 + (size_t)p * 4096 + o * 16;
        for (int ch = 0; ch < 64; ++ch) {
          float hv = (float)hrow[ch];
          bf16x8 wv0 = *(const bf16x8*)(wrow + ch * 64);
          bf16x8 wv1 = *(const bf16x8*)(wrow + ch * 64 + 8);
#pragma unroll
          for (int q = 0; q < 8; ++q) {
            part[q] += hv * (float)wv0[q];
            part[8 + q] += hv * (float)wv1[q];
          }
        }
      }
    }
    float* sacc = c0l;   // c0 dead after last step; 16 KB needed, 21.7 avail
#pragma unroll
    for (int q = 0; q < 16; ++q) sacc[pg * 64 + o * 16 + q] = part[q];
    __syncthreads();
    if (t < 64) {
      float s = fc1b[t];
      for (int pg2 = 0; pg2 < 64; ++pg2) s += sacc[pg2 * 64 + t];
      out[(size_t)b * 128 + t] = fmaxf(s, 0.f);
    } else if (t < 128) {
      int j = t - 64;
      float s = exb[j];
      for (int k = 0; k < 24; ++k) s += x_ex[b * 24 + k] * exw[j * 24 + k];
      out[(size_t)b * 128 + 64 + j] = fmaxf(s, 0.f);
    }
  }
}

// ---------------- launcher ----------------
extern "C" void kernel_launch(void* const* d_in, const int* in_sizes, int n_in,
                              void* d_out, int out_size, void* d_ws, size_t ws_size,
                              hipStream_t stream) {
  const float* input = (const float*)d_in[0];
  const float* x_ex  = (const float*)d_in[1];
  const float* Wx0   = (const float*)d_in[2];
  const float* bx0   = (const float*)d_in[3];
  const float* Wh0   = (const float*)d_in[4];
  const float* Wc0   = (const float*)d_in[5];
  const float* Wx1   = (const float*)d_in[6];
  const float* bx1   = (const float*)d_in[7];
  const float* Wh1   = (const float*)d_in[8];
  const float* Wc1   = (const float*)d_in[9];
  const float* fc1w  = (const float*)d_in[10];
  const float* fc1b  = (const float*)d_in[11];
  const float* exw   = (const float*)d_in[12];
  const float* exb   = (const float*)d_in[13];
  (void)in_sizes; (void)n_in;

  if (ws_size < WS_NEED) {
    hipMemsetAsync(d_out, 0, (size_t)out_size * 4, stream);
    return;
  }

  char* ws = (char*)d_ws;
  __bf16* wp0  = (__bf16*)(ws + OFF_WP0);
  __bf16* wp1  = (__bf16*)(ws + OFF_WP1);
  __bf16* wfc2 = (__bf16*)(ws + OFF_WFC);

  pack_w0<<<160, 256, 0, stream>>>(Wx0, Wh0, wp0);
  pack_w1<<<864, 256, 0, stream>>>(Wx1, Wh1, wp1);
  pack_wfc<<<2688, 256, 0, stream>>>(fc1w, wfc2);

  convlstm_persistent<<<2048, 256, 0, stream>>>(
      input, x_ex, wp0, wp1, wfc2, bx0, bx1, Wc0, Wc1, fc1b, exw, exb,
      (float*)d_out);
}

// Round 12
// 2998.095 us; speedup vs baseline: 1.5700x; 1.5700x over previous
//
#include <hip/hip_runtime.h>
#include <math.h>

// ConvLSTM encoder, MI355X. Batch-persistent: one block per batch element,
// 256 threads (4 waves). R12: LDS 65.9 KB (single h buffers + register-staged
// delayed commits; sx2 kept in LDS; c0 in registers) so 2 blocks/CU
// co-reside -> 2 waves/SIMD TLP, while keeping R10's spill-free register
// budget (~240). Convs = MFMA GEMMs (M=pixels, N=gates*ch, K=im2col taps
// from LDS), fragment-ordered weights streamed from L2 with unroll-2
// B-prefetch, single A-fragment buffer.

typedef __bf16 bf16x8 __attribute__((ext_vector_type(8)));
typedef float  f32x4  __attribute__((ext_vector_type(4)));

__device__ __forceinline__ float sigm(float x)  { return 1.f / (1.f + __expf(-x)); }
__device__ __forceinline__ float ftanh(float x) { float e = __expf(2.f * x); return 1.f - 2.f / (e + 1.f); }

// ---------------- workspace layout (bytes) ----------------
#define OFF_WP0  ((size_t)0)          // [2][10][4][64][8] bf16 = 81,920
#define OFF_WP1  ((size_t)81920)      // [4][27][4][64][8] bf16 = 442,368
#define OFF_WFC  ((size_t)524288)     // [168][64][64] bf16 = 1,376,256
#define WS_NEED  ((size_t)1900544)

// ---------------- weight pack kernels (fragment-ordered) ----------------
// wp0f[((chh*10+s)*4+g)*512 + L*8 + e] = W0(n = g*32+chh*16+(L&15),
//   k = s*32+(L>>4)*8+e); k<32 = im2col-x (k<18 real), k>=32 h0 taps.
__global__ void pack_w0(const float* __restrict__ wx0, const float* __restrict__ wh0,
                        __bf16* __restrict__ dst) {
  int o = blockIdx.x * 256 + threadIdx.x;
  if (o >= 40960) return;
  int e = o & 7, L = (o >> 3) & 63;
  int idx = o >> 9;
  int g = idx & 3, sidx = idx >> 2;
  int s = sidx % 10, chh = sidx / 10;
  int n = g * 32 + chh * 16 + (L & 15);
  int k = s * 32 + (L >> 4) * 8 + e;
  float v = 0.f;
  if (k < 32) {
    if (k < 18) {
      int ky = k / 6, rem = k - ky * 6, kx = rem >> 1, ci = rem & 1;
      v = wx0[(n * 2 + ci) * 9 + ky * 3 + kx];
    }
  } else {
    int tk = k - 32, tap = tk >> 5, c = tk & 31;
    v = wh0[(n * 32 + c) * 9 + tap];
  }
  dst[o] = (__bf16)v;
}

// wp1f[((chq*27+s)*4+g)*512 + L*8 + e]: s=0..8 Wx1 taps (on h0(t), cin=32);
// s=9..26 Wh1 (tap,half) chunks (cin=64).
__global__ void pack_w1(const float* __restrict__ wx1, const float* __restrict__ wh1,
                        __bf16* __restrict__ dst) {
  int o = blockIdx.x * 256 + threadIdx.x;
  if (o >= 221184) return;
  int e = o & 7, L = (o >> 3) & 63;
  int idx = o >> 9;
  int g = idx & 3, sidx = idx >> 2;
  int s = sidx % 27, chq = sidx / 27;
  int n = g * 64 + chq * 16 + (L & 15);
  int k = s * 32 + (L >> 4) * 8 + e;
  float v;
  if (k < 288) {
    int tap = k >> 5, c = k & 31;
    v = wx1[(n * 32 + c) * 9 + tap];
  } else {
    int tk = k - 288, s2 = tk >> 5, c = tk & 31, tap = s2 >> 1, hf = s2 & 1;
    v = wh1[(n * 64 + hf * 32 + c) * 9 + tap];
  }
  dst[o] = (__bf16)v;
}

// Wfc2[pix][ch][n] bf16 = fc1_w[n][ch*168+pix]
__global__ void pack_wfc(const float* __restrict__ w, __bf16* __restrict__ dst) {
  int o = blockIdx.x * 256 + threadIdx.x;
  if (o >= 168 * 64 * 64) return;
  int pix = o >> 12, ch = (o >> 6) & 63, n = o & 63;
  dst[o] = (__bf16)w[n * 10752 + ch * 168 + pix];
}

// ---------------- the persistent ConvLSTM kernel ----------------
__global__ __launch_bounds__(256) void convlstm_persistent(
    const float* __restrict__ input, const float* __restrict__ x_ex,
    const __bf16* __restrict__ wp0, const __bf16* __restrict__ wp1,
    const __bf16* __restrict__ wfc2,
    const float* __restrict__ bx0, const float* __restrict__ bx1,
    const float* __restrict__ wc0, const float* __restrict__ wc1,
    const float* __restrict__ fc1b,
    const float* __restrict__ exw, const float* __restrict__ exb,
    float* __restrict__ out)
{
  __shared__ __bf16 sh0[9 * 26 * 40];   // h0 halo [y][x][40]  18,720 B
  __shared__ __bf16 sh1[9 * 26 * 72];   // h1 halo [y][x][72]  33,696 B
  __shared__ __bf16 sx2[168 * 40];      // im2col x [pix][40]  13,440 B
  // total 65,856 B -> 2 blocks/CU -> 2 waves/SIMD

  const int b = blockIdx.x;
  const int t = threadIdx.x;
  const int w = t >> 6, L = t & 63;
  const int lo16 = L & 15, hi4 = L >> 4;

  // ---- zero LDS ----
  {
    int* p0 = (int*)sh0;
    for (int i = t; i < 9 * 26 * 40 / 2; i += 256) p0[i] = 0;
    int* p1 = (int*)sh1;
    for (int i = t; i < 9 * 26 * 72 / 2; i += 256) p1[i] = 0;
    int* p2 = (int*)sx2;
    for (int i = t; i < 168 * 40 / 2; i += 256) p2[i] = 0;
  }
  __syncthreads();

  // ---- build im2col x2 [pix][40], k = ky*6+kx*2+cin (k<18 real) ----
  if (t < 168) {
    int iy = t / 24, ix = t - iy * 24;
    __bf16* dst = sx2 + t * 40;
    for (int ky = 0; ky < 3; ++ky) {
      int y = iy + ky - 1;
      if (y < 0 || y >= 7) continue;
      for (int kx = 0; kx < 3; ++kx) {
        int x = ix + kx - 1;
        if (x < 0 || x >= 24) continue;
        int k0 = ky * 6 + kx * 2;
        dst[k0 + 0] = (__bf16)input[((b * 2 + 0) * 7 + y) * 24 + x];
        dst[k0 + 1] = (__bf16)input[((b * 2 + 1) * 7 + y) * 24 + x];
      }
    }
  }

  // ---- per-wave / per-lane constants ----
  const int mh = w >> 1, chh = w & 1;   // layer-0 wave role
  const int ch0 = chh * 16 + lo16;      // layer-0 channel (0..31)
  const int ch1 = w * 16 + lo16;        // layer-1 channel (0..63)

  const __bf16* w0f = wp0 + chh * 20480 + (size_t)L * 8;  // + (s*4+g)*512
  const __bf16* w1f = wp1 + w * 55296 + (size_t)L * 8;    // + (s*4+g)*512

  int b0h[2][3], b0x[2][3];
#pragma unroll
  for (int q = 0; q < 2; ++q)
#pragma unroll
    for (int j = 0; j < 3; ++j) {
      int pr = (mh * 6 + q * 3 + j) * 16 + lo16;
      if (pr > 167) pr = 167;
      int iy = pr / 24, ix = pr - iy * 24;
      b0h[q][j] = (iy * 26 + ix) * 40;
      b0x[q][j] = pr * 40 + hi4 * 8;
    }

  float c0r[2][3][4], c1r[4][3][4];
#pragma unroll
  for (int q = 0; q < 2; ++q)
#pragma unroll
    for (int j = 0; j < 3; ++j)
#pragma unroll
      for (int r = 0; r < 4; ++r) c0r[q][j][r] = 0.f;
#pragma unroll
  for (int p = 0; p < 4; ++p)
#pragma unroll
    for (int j = 0; j < 3; ++j)
#pragma unroll
      for (int r = 0; r < 4; ++r) c1r[p][j][r] = 0.f;

  auto pk2 = [](float a, float bb) -> unsigned {
    __bf16 xa = (__bf16)a, xb = (__bf16)bb;
    unsigned short ua, ub;
    __builtin_memcpy(&ua, &xa, 2);
    __builtin_memcpy(&ub, &xb, 2);
    return (unsigned)ua | ((unsigned)ub << 16);
  };
  unsigned short* sh0u = (unsigned short*)sh0;
  unsigned short* sh1u = (unsigned short*)sh1;

  __syncthreads();   // x2 + zeroed state visible

#pragma unroll 1
  for (int st = 0; st < 7; ++st) {
    // ======================= layer 0 =======================
    f32x4 a0[4][3];
    auto loadB0 = [&](int s, bf16x8* bc) {
#pragma unroll
      for (int g = 0; g < 4; ++g)
        bc[g] = *(const bf16x8*)(w0f + (s * 4 + g) * 512);
    };
    auto runK0 = [&](int q) {
#pragma unroll
      for (int g = 0; g < 4; ++g)
#pragma unroll
        for (int j = 0; j < 3; ++j) a0[g][j] = (f32x4){0.f, 0.f, 0.f, 0.f};
      auto loadA0 = [&](int s, bf16x8* af) {
        if (s == 0) {
#pragma unroll
          for (int j = 0; j < 3; ++j) af[j] = *(const bf16x8*)(sx2 + b0x[q][j]);
        } else {
          int tap = s - 1, ky = tap / 3, kx = tap - ky * 3;
          int toff = (ky * 26 + kx) * 40 + hi4 * 8;
#pragma unroll
          for (int j = 0; j < 3; ++j) af[j] = *(const bf16x8*)(sh0 + b0h[q][j] + toff);
        }
      };
      auto mfma0 = [&](bf16x8* af, bf16x8* bc) {
#pragma unroll
        for (int j = 0; j < 3; ++j)
#pragma unroll
          for (int g = 0; g < 4; ++g)
            a0[g][j] = __builtin_amdgcn_mfma_f32_16x16x32_bf16(af[j], bc[g], a0[g][j], 0, 0, 0);
      };
      bf16x8 bcA[4], bcB[4], afT[3];
      loadB0(0, bcA); loadB0(1, bcB);
#pragma unroll 1
      for (int s = 0; s < 10; s += 2) {
        loadA0(s, afT); mfma0(afT, bcA);
        loadB0((s + 2 < 10) ? s + 2 : 9, bcA);
        loadA0(s + 1, afT); mfma0(afT, bcB);
        loadB0((s + 3 < 10) ? s + 3 : 9, bcB);
      }
    };

    // pass 0: K + epilogue -> stage
    unsigned st0[6];
    runK0(0);
    {
      const float bi0 = bx0[ch0], bf0 = bx0[32 + ch0];
      const float bg0 = bx0[64 + ch0], bo0 = bx0[96 + ch0];
#pragma unroll
      for (int j = 0; j < 3; ++j) {
#pragma unroll
        for (int r = 0; r < 4; r += 2) {
          float hn2[2];
#pragma unroll
          for (int rr = 0; rr < 2; ++rr) {
            int r2 = r + rr;
            int p = (mh * 6 + j) * 16 + hi4 * 4 + r2;
            float c = c0r[0][j][r2];
            float gi = a0[0][j][r2] + bi0;
            float gf = a0[1][j][r2] + bf0;
            float gc = a0[2][j][r2] + bg0;
            float go = a0[3][j][r2] + bo0;
            float wci = wc0[ch0 * 168 + p];
            float wcf = wc0[5376 + ch0 * 168 + p];
            float wco = wc0[10752 + ch0 * 168 + p];
            float ig = sigm(gi + c * wci);
            float fg = sigm(gf + c * wcf);
            float cn = fg * c + ig * ftanh(gc);
            float og = sigm(go + cn * wco);
            c0r[0][j][r2] = cn;
            hn2[rr] = og * ftanh(cn);
          }
          st0[j * 2 + (r >> 1)] = pk2(hn2[0], hn2[1]);
        }
      }
    }
    // pass 1: K; barrier; commit pass-0; pass-1 epilogue direct (masked)
    runK0(1);
    __syncthreads();   // all h0(t-1)/x2 reads done
#pragma unroll
    for (int j = 0; j < 3; ++j)
#pragma unroll
      for (int r = 0; r < 4; ++r) {
        int p = (mh * 6 + j) * 16 + hi4 * 4 + r;
        int iy = p / 24, ix = p - iy * 24;
        unsigned v = st0[j * 2 + (r >> 1)] >> ((r & 1) * 16);
        sh0u[((iy + 1) * 26 + ix + 1) * 40 + ch0] = (unsigned short)v;
      }
    {
      const float bi0 = bx0[ch0], bf0 = bx0[32 + ch0];
      const float bg0 = bx0[64 + ch0], bo0 = bx0[96 + ch0];
#pragma unroll
      for (int j = 0; j < 3; ++j) {
#pragma unroll
        for (int r = 0; r < 4; ++r) {
          int p = (mh * 6 + 3 + j) * 16 + hi4 * 4 + r;
          if (p < 168) {
            float c = c0r[1][j][r];
            float gi = a0[0][j][r] + bi0;
            float gf = a0[1][j][r] + bf0;
            float gc = a0[2][j][r] + bg0;
            float go = a0[3][j][r] + bo0;
            float wci = wc0[ch0 * 168 + p];
            float wcf = wc0[5376 + ch0 * 168 + p];
            float wco = wc0[10752 + ch0 * 168 + p];
            float ig = sigm(gi + c * wci);
            float fg = sigm(gf + c * wcf);
            float cn = fg * c + ig * ftanh(gc);
            float og = sigm(go + cn * wco);
            float hn = og * ftanh(cn);
            c0r[1][j][r] = cn;
            int iy = p / 24, ix = p - iy * 24;
            sh0[((iy + 1) * 26 + ix + 1) * 40 + ch0] = (__bf16)hn;
          }
        }
      }
    }
    __syncthreads();   // h0(t) visible

    // ======================= layer 1: 4 M-passes =======================
    f32x4 a1[4][3];
    auto loadB1 = [&](int s, bf16x8* bc) {
#pragma unroll
      for (int g = 0; g < 4; ++g)
        bc[g] = *(const bf16x8*)(w1f + (s * 4 + g) * 512);
    };
    auto runK1 = [&](int p4, int ntp) {
      int b1h0[3], b1h1[3];
#pragma unroll
      for (int j = 0; j < 3; ++j) {
        int pr = (p4 * 3 + j) * 16 + lo16;
        if (pr > 167) pr = 167;
        int iy = pr / 24, ix = pr - iy * 24;
        b1h0[j] = (iy * 26 + ix) * 40;
        b1h1[j] = (iy * 26 + ix) * 72;
      }
#pragma unroll
      for (int g = 0; g < 4; ++g)
#pragma unroll
        for (int j = 0; j < 3; ++j) a1[g][j] = (f32x4){0.f, 0.f, 0.f, 0.f};
      auto loadA1 = [&](int s, bf16x8* af) {
        if (s < 9) {
          int ky = s / 3, kx = s - ky * 3;
          int toff = (ky * 26 + kx) * 40 + hi4 * 8;
#pragma unroll
          for (int j = 0; j < 3; ++j)
            if (j < ntp) af[j] = *(const bf16x8*)(sh0 + b1h0[j] + toff);
        } else {
          int t2 = s - 9, tap = t2 >> 1, hf = t2 & 1;
          int ky = tap / 3, kx = tap - ky * 3;
          int toff = (ky * 26 + kx) * 72 + hf * 32 + hi4 * 8;
#pragma unroll
          for (int j = 0; j < 3; ++j)
            if (j < ntp) af[j] = *(const bf16x8*)(sh1 + b1h1[j] + toff);
        }
      };
      auto mfma1 = [&](bf16x8* af, bf16x8* bc) {
#pragma unroll
        for (int j = 0; j < 3; ++j)
          if (j < ntp)
#pragma unroll
            for (int g = 0; g < 4; ++g)
              a1[g][j] = __builtin_amdgcn_mfma_f32_16x16x32_bf16(af[j], bc[g], a1[g][j], 0, 0, 0);
      };
      bf16x8 bcA[4], bcB[4], afT[3];
      loadB1(0, bcA); loadB1(1, bcB);
#pragma unroll 1
      for (int s = 0; s < 26; s += 2) {
        loadA1(s, afT); mfma1(afT, bcA);
        loadB1((s + 2 < 27) ? s + 2 : 26, bcA);
        loadA1(s + 1, afT); mfma1(afT, bcB);
        loadB1((s + 3 < 27) ? s + 3 : 26, bcB);
      }
      loadA1(26, afT); mfma1(afT, bcA);
    };
    auto epi1_stage = [&](int p4, unsigned* stg) {
      const float bi1 = bx1[ch1], bf1 = bx1[64 + ch1];
      const float bg1 = bx1[128 + ch1], bo1 = bx1[192 + ch1];
#pragma unroll
      for (int j = 0; j < 3; ++j) {
#pragma unroll
        for (int r = 0; r < 4; r += 2) {
          float hn2[2];
#pragma unroll
          for (int rr = 0; rr < 2; ++rr) {
            int r2 = r + rr;
            int p = (p4 * 3 + j) * 16 + hi4 * 4 + r2;
            float c = c1r[p4][j][r2];
            float gi = a1[0][j][r2] + bi1;
            float gf = a1[1][j][r2] + bf1;
            float gc = a1[2][j][r2] + bg1;
            float go = a1[3][j][r2] + bo1;
            float wci = wc1[ch1 * 168 + p];
            float wcf = wc1[10752 + ch1 * 168 + p];
            float wco = wc1[21504 + ch1 * 168 + p];
            float ig = sigm(gi + c * wci);
            float fg = sigm(gf + c * wcf);
            float cn = fg * c + ig * ftanh(gc);
            float og = sigm(go + cn * wco);
            c1r[p4][j][r2] = cn;
            hn2[rr] = og * ftanh(cn);
          }
          stg[j * 2 + (r >> 1)] = pk2(hn2[0], hn2[1]);
        }
      }
    };
    auto commit1 = [&](int p4, const unsigned* stg) {
#pragma unroll
      for (int j = 0; j < 3; ++j)
#pragma unroll
        for (int r = 0; r < 4; ++r) {
          int p = (p4 * 3 + j) * 16 + hi4 * 4 + r;
          int iy = p / 24, ix = p - iy * 24;
          unsigned v = stg[j * 2 + (r >> 1)] >> ((r & 1) * 16);
          sh1u[((iy + 1) * 26 + ix + 1) * 72 + ch1] = (unsigned short)v;
        }
    };

    unsigned stg[6];
    runK1(0, 3);
    epi1_stage(0, stg);
    runK1(1, 3);
    __syncthreads();            // pass-0/1 h1(t-1) reads done
    commit1(0, stg);
    epi1_stage(1, stg);
    runK1(2, 3);
    __syncthreads();            // pass-2 h1(t-1) reads done
    commit1(1, stg);
    epi1_stage(2, stg);
    runK1(3, 2);
    __syncthreads();            // all h1(t-1) reads done
    commit1(2, stg);
    {  // pass-3 epilogue: direct write (masked)
      const float bi1 = bx1[ch1], bf1 = bx1[64 + ch1];
      const float bg1 = bx1[128 + ch1], bo1 = bx1[192 + ch1];
#pragma unroll
      for (int j = 0; j < 2; ++j) {
#pragma unroll
        for (int r = 0; r < 4; ++r) {
          int p = (9 + j) * 16 + hi4 * 4 + r;
          if (p < 168) {
            float c = c1r[3][j][r];
            float gi = a1[0][j][r] + bi1;
            float gf = a1[1][j][r] + bf1;
            float gc = a1[2][j][r] + bg1;
            float go = a1[3][j][r] + bo1;
            float wci = wc1[ch1 * 168 + p];
            float wcf = wc1[10752 + ch1 * 168 + p];
            float wco = wc1[21504 + ch1 * 168 + p];
            float ig = sigm(gi + c * wci);
            float fg = sigm(gf + c * wcf);
            float cn = fg * c + ig * ftanh(gc);
            float og = sigm(go + cn * wco);
            float hn = og * ftanh(cn);
            c1r[3][j][r] = cn;
            int iy = p / 24, ix = p - iy * 24;
            sh1[((iy + 1) * 26 + ix + 1) * 72 + ch1] = (__bf16)hn;
          }
        }
      }
    }
    // no trailing barrier needed: next readers of sh1 are behind >=2 barriers
  }

  // ================= FC heads (h1 final in sh1) =================
  {
    __syncthreads();                     // h1(7) writes visible
    const int o = t & 3, pg = t >> 2;    // o: 16 n's (o*16..); pg 0..63
    float part[16];
#pragma unroll
    for (int q = 0; q < 16; ++q) part[q] = 0.f;
#pragma unroll 1
    for (int jj = 0; jj < 3; ++jj) {
      int p = pg + 64 * jj;
      if (p < 168) {
        int iy = p / 24, ix = p - iy * 24;
        const __bf16* hrow = sh1 + ((iy + 1) * 26 + ix + 1) * 72;
        const __bf16* wrow = wfc2 + (size_t)p * 4096 + o * 16;
        for (int ch = 0; ch < 64; ++ch) {
          float hv = (float)hrow[ch];
          bf16x8 wv0 = *(const bf16x8*)(wrow + ch * 64);
          bf16x8 wv1 = *(const bf16x8*)(wrow + ch * 64 + 8);
#pragma unroll
          for (int q = 0; q < 8; ++q) {
            part[q] += hv * (float)wv0[q];
            part[8 + q] += hv * (float)wv1[q];
          }
        }
      }
    }
    float* sacc = (float*)sh0;   // sh0 dead; 16 KB needed, 18.7 KB avail
#pragma unroll
    for (int q = 0; q < 16; ++q) sacc[pg * 64 + o * 16 + q] = part[q];
    __syncthreads();
    if (t < 64) {
      float s = fc1b[t];
      for (int pg2 = 0; pg2 < 64; ++pg2) s += sacc[pg2 * 64 + t];
      out[(size_t)b * 128 + t] = fmaxf(s, 0.f);
    } else if (t < 128) {
      int j = t - 64;
      float s = exb[j];
      for (int k = 0; k < 24; ++k) s += x_ex[b * 24 + k] * exw[j * 24 + k];
      out[(size_t)b * 128 + 64 + j] = fmaxf(s, 0.f);
    }
  }
}

// ---------------- launcher ----------------
extern "C" void kernel_launch(void* const* d_in, const int* in_sizes, int n_in,
                              void* d_out, int out_size, void* d_ws, size_t ws_size,
                              hipStream_t stream) {
  const float* input = (const float*)d_in[0];
  const float* x_ex  = (const float*)d_in[1];
  const float* Wx0   = (const float*)d_in[2];
  const float* bx0   = (const float*)d_in[3];
  const float* Wh0   = (const float*)d_in[4];
  const float* Wc0   = (const float*)d_in[5];
  const float* Wx1   = (const float*)d_in[6];
  const float* bx1   = (const float*)d_in[7];
  const float* Wh1   = (const float*)d_in[8];
  const float* Wc1   = (const float*)d_in[9];
  const float* fc1w  = (const float*)d_in[10];
  const float* fc1b  = (const float*)d_in[11];
  const float* exw   = (const float*)d_in[12];
  const float* exb   = (const float*)d_in[13];
  (void)in_sizes; (void)n_in;

  if (ws_size < WS_NEED) {
    hipMemsetAsync(d_out, 0, (size_t)out_size * 4, stream);
    return;
  }

  char* ws = (char*)d_ws;
  __bf16* wp0  = (__bf16*)(ws + OFF_WP0);
  __bf16* wp1  = (__bf16*)(ws + OFF_WP1);
  __bf16* wfc2 = (__bf16*)(ws + OFF_WFC);

  pack_w0<<<160, 256, 0, stream>>>(Wx0, Wh0, wp0);
  pack_w1<<<864, 256, 0, stream>>>(Wx1, Wh1, wp1);
  pack_wfc<<<2688, 256, 0, stream>>>(fc1w, wfc2);

  convlstm_persistent<<<2048, 256, 0, stream>>>(
      input, x_ex, wp0, wp1, wfc2, bx0, bx1, Wc0, Wc1, fc1b, exw, exb,
      (float*)d_out);
}